// Round 2
// baseline (539.986 us; speedup 1.0000x reference)
//
#include <hip/hip_runtime.h>
#include <stdint.h>

typedef unsigned short u16;
typedef u16   u16x4v __attribute__((ext_vector_type(4)));
typedef u16   u16x8v __attribute__((ext_vector_type(8)));
typedef short s16x8v __attribute__((ext_vector_type(8)));
typedef float f32x4v __attribute__((ext_vector_type(4)));
typedef float f32x2v __attribute__((ext_vector_type(2)));

#define DEV static __device__ __forceinline__

// fp32 -> bf16 round-to-nearest-even
DEV u16 f2bf(float f){
  union { float f; unsigned u; } v; v.f = f;
  unsigned r = v.u + 0x7FFFu + ((v.u >> 16) & 1u);
  return (u16)(r >> 16);
}

DEV f32x4v mfma16(s16x8v a, s16x8v b, f32x4v c){
  return __builtin_amdgcn_mfma_f32_16x16x32_bf16(a, b, c, 0, 0, 0);
}

// ---------------------------------------------------------------------------
// K0: w (8,512,64) fp32 -> wt[n=h*64+k][d] bf16
__global__ __launch_bounds__(256) void k_wt(const float* __restrict__ w, u16* __restrict__ wt){
  int e = blockIdx.x * 256 + threadIdx.x;     // = n*512 + d
  int n = e >> 9, d = e & 511;
  int h = n >> 6, kk = n & 63;
  wt[e] = f2bf(w[h * 32768 + d * 64 + kk]);
}

// ---------------------------------------------------------------------------
// K1: Y = X @ Wt^T.  X fp32 (8192x512), Wt bf16 (512x512 row-major [n][d]).
// MODE 0: head-major bf16 out: Y[(h*4+b)*2048+m][dk], scaled by `scale`
// MODE 1: V transposed+k-permuted out: Y[n][pi(i)]  (for direct PV B-frags)
template<int MODE>
__global__ __launch_bounds__(256) void k_proj(const float* __restrict__ X,
                                              const u16* __restrict__ Wt,
                                              u16* __restrict__ Y, float scale){
  __shared__ __align__(16) u16 Xs[64 * 72];
  __shared__ __align__(16) u16 Ws[64 * 72];
  const int t = threadIdx.x;
  const int lane = t & 63, w = t >> 6;
  const int g = lane >> 4, li = lane & 15;
  const int i0 = blockIdx.x * 64;
  const int n0 = blockIdx.y * 64;
  f32x4v acc[4] = {};
  for(int kc = 0; kc < 512; kc += 64){
    __syncthreads();
    #pragma unroll
    for(int it = 0; it < 4; ++it){
      int eidx = it * 256 + t, row = eidx >> 4, q4 = eidx & 15;
      f32x4v xv = *(const f32x4v*)(X + (size_t)(i0 + row) * 512 + kc + q4 * 4);
      u16x4v bv; bv[0]=f2bf(xv[0]); bv[1]=f2bf(xv[1]); bv[2]=f2bf(xv[2]); bv[3]=f2bf(xv[3]);
      *(u16x4v*)(Xs + row * 72 + q4 * 4) = bv;
    }
    #pragma unroll
    for(int it = 0; it < 2; ++it){
      int eidx = it * 256 + t, row = eidx >> 3, c8 = eidx & 7;
      u16x8v wv = *(const u16x8v*)(Wt + (size_t)(n0 + row) * 512 + kc + c8 * 8);
      *(u16x8v*)(Ws + row * 72 + c8 * 8) = wv;
    }
    __syncthreads();
    #pragma unroll
    for(int s = 0; s < 2; ++s){
      int k0 = s * 32 + g * 8;           // contiguous k-bijection (A/B consistent)
      s16x8v a = *(const s16x8v*)(Xs + (w * 16 + li) * 72 + k0);
      #pragma unroll
      for(int j = 0; j < 4; ++j){
        s16x8v b = *(const s16x8v*)(Ws + (j * 16 + li) * 72 + k0);
        acc[j] = mfma16(a, b, acc[j]);
      }
    }
  }
  if(MODE == 0){
    #pragma unroll
    for(int j = 0; j < 4; ++j){
      int n = n0 + j * 16 + li, hh = n >> 6, dk = n & 63;
      #pragma unroll
      for(int r = 0; r < 4; ++r){
        int i = i0 + w * 16 + g * 4 + r, bb = i >> 11, m = i & 2047;
        Y[((size_t)(hh * 4 + bb) * 2048 + m) * 64 + dk] = f2bf(acc[j][r] * scale);
      }
    }
  } else {
    // interleaved-bijection permutation within each 32-row block:
    // pi(m) = (m&~31) | ((m>>2)&3)<<3 | ((m>>4)&1)<<2 | (m&3)
    int ibase = i0 + w * 16 + g * 4;   // multiple of 4
    int pi = (ibase & ~31) | (((ibase >> 2) & 3) << 3) | (((ibase >> 4) & 1) << 2);
    #pragma unroll
    for(int j = 0; j < 4; ++j){
      int n = n0 + j * 16 + li;
      u16x4v pk;
      #pragma unroll
      for(int r = 0; r < 4; ++r) pk[r] = f2bf(acc[j][r]);
      *(u16x4v*)(Y + (size_t)n * 8192 + pi) = pk;
    }
  }
}

// ---------------------------------------------------------------------------
// K2: attention. No LDS, no barriers. Swapped QK^T (A=K, B=Q) so each lane
// owns q = lane&15: softmax stats are per-lane scalars. PV consumes P directly
// from registers via the interleaved k-bijection matched by vtt's layout.
__global__ __launch_bounds__(256) void k_attn(const u16* __restrict__ QHH, const u16* __restrict__ KHH,
                                              const u16* __restrict__ VTT, u16* __restrict__ XC,
                                              float* __restrict__ ATT){
  const int t = threadIdx.x, lane = t & 63, w = t >> 6;
  const int g = lane >> 4, li = lane & 15;
  const int lt = blockIdx.x;                 // q tile (0..31)
  const int hb = blockIdx.y;                 // h*4 + b
  const int h = hb >> 2, b = hb & 3;
  const size_t base_hb = (size_t)hb * 2048;

  // Q fragments for this wave's 16 q-rows (q = lt*64 + w*16 + li)
  s16x8v bq[2];
  {
    const u16* qp = QHH + (base_hb + lt * 64 + w * 16 + li) * 64;
    bq[0] = *(const s16x8v*)(qp + g * 8);
    bq[1] = *(const s16x8v*)(qp + 32 + g * 8);
  }
  const u16* kp_base = KHH + base_hb * 64;

  float m_s = -1e30f, l_s = 0.f;
  // ---- pass A: online max + sumexp (per-lane scalars) ----
  for(int mc = 0; mc < 32; ++mc){
    f32x4v sa[4];
    #pragma unroll
    for(int jm = 0; jm < 4; ++jm){
      const u16* kp = kp_base + (size_t)(mc * 64 + jm * 16 + li) * 64 + g * 8;
      f32x4v z = {};
      z = mfma16(*(const s16x8v*)(kp),      bq[0], z);
      z = mfma16(*(const s16x8v*)(kp + 32), bq[1], z);
      sa[jm] = z;
    }
    float mx = -1e30f;
    #pragma unroll
    for(int jm = 0; jm < 4; ++jm)
      #pragma unroll
      for(int r = 0; r < 4; ++r) mx = fmaxf(mx, sa[jm][r]);
    mx = fmaxf(mx, __shfl_xor(mx, 16, 64));
    mx = fmaxf(mx, __shfl_xor(mx, 32, 64));
    float nm = fmaxf(m_s, mx);
    float ts = 0.f;
    #pragma unroll
    for(int jm = 0; jm < 4; ++jm)
      #pragma unroll
      for(int r = 0; r < 4; ++r) ts += __expf(sa[jm][r] - nm);
    ts += __shfl_xor(ts, 16, 64);
    ts += __shfl_xor(ts, 32, 64);
    l_s = l_s * __expf(m_s - nm) + ts;
    m_s = nm;
  }
  const float rl_s = 1.0f / l_s;

  // ---- pass B: recompute S, write normalized attn (float4), PV ----
  f32x4v acco[4] = {};
  float* attb = ATT + base_hb * 2048 + (size_t)(lt * 64 + w * 16 + li) * 2048;
  for(int mc = 0; mc < 32; ++mc){
    f32x4v pa[4];
    #pragma unroll
    for(int jm = 0; jm < 4; ++jm){
      const u16* kp = kp_base + (size_t)(mc * 64 + jm * 16 + li) * 64 + g * 8;
      f32x4v z = {};
      z = mfma16(*(const s16x8v*)(kp),      bq[0], z);
      z = mfma16(*(const s16x8v*)(kp + 32), bq[1], z);
      #pragma unroll
      for(int r = 0; r < 4; ++r) pa[jm][r] = __expf(z[r] - m_s) * rl_s;
      *(f32x4v*)(attb + mc * 64 + jm * 16 + g * 4) = pa[jm];
    }
    // pack P into PV A-frags: chunk s slots = {s*32+g*4+r} U {s*32+16+g*4+r}
    s16x8v apv[2];
    #pragma unroll
    for(int s = 0; s < 2; ++s){
      union { u16 hh[8]; s16x8v v; } u;
      #pragma unroll
      for(int r = 0; r < 4; ++r){ u.hh[r] = f2bf(pa[2*s][r]); u.hh[4+r] = f2bf(pa[2*s+1][r]); }
      apv[s] = u.v;
    }
    #pragma unroll
    for(int j = 0; j < 4; ++j){
      const u16* vp = VTT + (size_t)(h * 64 + j * 16 + li) * 8192 + b * 2048 + mc * 64 + g * 8;
      acco[j] = mfma16(apv[0], *(const s16x8v*)(vp),      acco[j]);
      acco[j] = mfma16(apv[1], *(const s16x8v*)(vp + 32), acco[j]);
    }
  }
  #pragma unroll
  for(int j = 0; j < 4; ++j)
    #pragma unroll
    for(int r = 0; r < 4; ++r){
      int qrow = lt * 64 + w * 16 + g * 4 + r;
      XC[(size_t)(b * 2048 + qrow) * 512 + h * 64 + j * 16 + li] = f2bf(acco[j][r]);
    }
}

// ---------------------------------------------------------------------------
// K3a: Z[i][d] = sum_c Xb[i][c]*proj_w[d][c] + bias[d] + resid[i][d]   (fp32 out)
__global__ __launch_bounds__(256) void k_out_proj(const u16* __restrict__ Xb,
                                                  const float* __restrict__ Wp,
                                                  const float* __restrict__ bias,
                                                  const float* __restrict__ resid,
                                                  float* __restrict__ Z){
  __shared__ __align__(16) u16 Xs[64 * 72];
  __shared__ __align__(16) u16 Ws[64 * 72];
  const int t = threadIdx.x;
  const int lane = t & 63, w = t >> 6;
  const int g = lane >> 4, li = lane & 15;
  const int i0 = blockIdx.x * 64;
  const int n0 = blockIdx.y * 64;
  f32x4v acc[4] = {};
  for(int kc = 0; kc < 512; kc += 64){
    __syncthreads();
    #pragma unroll
    for(int it = 0; it < 2; ++it){
      int eidx = it * 256 + t, row = eidx >> 3, c8 = eidx & 7;
      u16x8v xv = *(const u16x8v*)(Xb + (size_t)(i0 + row) * 512 + kc + c8 * 8);
      *(u16x8v*)(Xs + row * 72 + c8 * 8) = xv;
    }
    #pragma unroll
    for(int it = 0; it < 4; ++it){
      int eidx = it * 256 + t, row = eidx >> 4, q4 = eidx & 15;
      f32x4v wv = *(const f32x4v*)(Wp + (size_t)(n0 + row) * 512 + kc + q4 * 4);
      u16x4v bv; bv[0]=f2bf(wv[0]); bv[1]=f2bf(wv[1]); bv[2]=f2bf(wv[2]); bv[3]=f2bf(wv[3]);
      *(u16x4v*)(Ws + row * 72 + q4 * 4) = bv;
    }
    __syncthreads();
    #pragma unroll
    for(int s = 0; s < 2; ++s){
      int k0 = s * 32 + g * 8;
      s16x8v a = *(const s16x8v*)(Xs + (w * 16 + li) * 72 + k0);
      #pragma unroll
      for(int j = 0; j < 4; ++j){
        s16x8v b = *(const s16x8v*)(Ws + (j * 16 + li) * 72 + k0);
        acc[j] = mfma16(a, b, acc[j]);
      }
    }
  }
  #pragma unroll
  for(int j = 0; j < 4; ++j)
    #pragma unroll
    for(int r = 0; r < 4; ++r){
      int row = i0 + w * 16 + g * 4 + r;
      int col = n0 + j * 16 + li;
      Z[(size_t)row * 512 + col] = acc[j][r] + bias[col] + resid[(size_t)row * 512 + col];
    }
}

// ---------------------------------------------------------------------------
// K3b: row LayerNorm, torch semantics: (z-mu)/(std_ddof1 + eps)*a2 + b2
__global__ __launch_bounds__(256) void k_ln(const float* __restrict__ Z,
                                            const float* __restrict__ a2,
                                            const float* __restrict__ b2,
                                            float* __restrict__ out){
  __shared__ float red[8];
  const int i = blockIdx.x, t = threadIdx.x;
  const float* z = Z + (size_t)i * 512;
  f32x2v v = *(const f32x2v*)(z + t * 2);
  float s = v[0] + v[1], sq = v[0] * v[0] + v[1] * v[1];
  #pragma unroll
  for(int off = 1; off < 64; off <<= 1){
    s  += __shfl_xor(s,  off, 64);
    sq += __shfl_xor(sq, off, 64);
  }
  const int wid = t >> 6;
  if((t & 63) == 0){ red[wid] = s; red[4 + wid] = sq; }
  __syncthreads();
  float S  = red[0] + red[1] + red[2] + red[3];
  float SQ = red[4] + red[5] + red[6] + red[7];
  float mu = S * (1.0f / 512.0f);
  float var = (SQ - 512.0f * mu * mu) * (1.0f / 511.0f);
  float sigma = sqrtf(fmaxf(var, 0.0f));
  float rs = 1.0f / (sigma + 1e-3f);
  f32x2v o;
  o[0] = (v[0] - mu) * rs * a2[t * 2]     + b2[t * 2];
  o[1] = (v[1] - mu) * rs * a2[t * 2 + 1] + b2[t * 2 + 1];
  *(f32x2v*)(out + (size_t)i * 512 + t * 2) = o;
}

// ---------------------------------------------------------------------------
extern "C" void kernel_launch(void* const* d_in, const int* in_sizes, int n_in,
                              void* d_out, int out_size, void* d_ws, size_t ws_size,
                              hipStream_t stream){
  const float* q      = (const float*)d_in[0];
  const float* k      = (const float*)d_in[1];
  const float* v      = (const float*)d_in[2];
  const float* w_qs   = (const float*)d_in[3];
  const float* w_ks   = (const float*)d_in[4];
  const float* w_vs   = (const float*)d_in[5];
  const float* proj_w = (const float*)d_in[6];
  const float* proj_b = (const float*)d_in[7];
  const float* a2     = (const float*)d_in[8];
  const float* b2     = (const float*)d_in[9];

  char* ws = (char*)d_ws;
  u16* wt    = (u16*)(ws);                       // 1.5 MB
  u16* qhh   = (u16*)(ws + 1572864);             // 8 MB, head-major [hb][m][dk], pre-scaled
  u16* khh   = (u16*)(ws + 9961472);             // 8 MB, head-major
  u16* vtt   = (u16*)(ws + 18350080);            // 8 MB, [n=h*64+dv][pi(i)]
  u16* xc    = (u16*)(ws + 26738688);            // 8 MB, row-major [i][512]
  float* zbuf= (float*)(ws + 35127296);          // 16 MB

  float* out = (float*)d_out;                    // (4,2048,512) fp32
  float* att = out + 4194304;                    // (32,2048,2048) fp32

  const float rtemper = 0.044194173824159216f;   // 1/sqrt(512)

  k_wt<<<dim3(1024), 256, 0, stream>>>(w_qs, wt);
  k_wt<<<dim3(1024), 256, 0, stream>>>(w_ks, wt + 262144);
  k_wt<<<dim3(1024), 256, 0, stream>>>(w_vs, wt + 524288);

  k_proj<0><<<dim3(128, 8), 256, 0, stream>>>(q, wt,          qhh, rtemper);
  k_proj<0><<<dim3(128, 8), 256, 0, stream>>>(k, wt + 262144, khh, 1.0f);
  k_proj<1><<<dim3(128, 8), 256, 0, stream>>>(v, wt + 524288, vtt, 1.0f);

  k_attn<<<dim3(32, 32), 256, 0, stream>>>(qhh, khh, vtt, xc, att);

  k_out_proj<<<dim3(128, 8), 256, 0, stream>>>(xc, proj_w, proj_b, q, zbuf);
  k_ln<<<dim3(8192), 256, 0, stream>>>(zbuf, a2, b2, out);
}

// Round 3
// 331.452 us; speedup vs baseline: 1.6292x; 1.6292x over previous
//
#include <hip/hip_runtime.h>
#include <stdint.h>

typedef unsigned short u16;
typedef u16   u16x4v __attribute__((ext_vector_type(4)));
typedef u16   u16x8v __attribute__((ext_vector_type(8)));
typedef short s16x8v __attribute__((ext_vector_type(8)));
typedef float f32x4v __attribute__((ext_vector_type(4)));
typedef float f32x2v __attribute__((ext_vector_type(2)));

#define DEV static __device__ __forceinline__

// fp32 -> bf16 round-to-nearest-even
DEV u16 f2bf(float f){
  union { float f; unsigned u; } v; v.f = f;
  unsigned r = v.u + 0x7FFFu + ((v.u >> 16) & 1u);
  return (u16)(r >> 16);
}

DEV f32x4v mfma16(s16x8v a, s16x8v b, f32x4v c){
  return __builtin_amdgcn_mfma_f32_16x16x32_bf16(a, b, c, 0, 0, 0);
}

// ---------------------------------------------------------------------------
// K0: w (8,512,64) fp32 -> wt[n=h*64+k][d] bf16
__global__ __launch_bounds__(256) void k_wt(const float* __restrict__ w, u16* __restrict__ wt){
  int e = blockIdx.x * 256 + threadIdx.x;     // = n*512 + d
  int n = e >> 9, d = e & 511;
  int h = n >> 6, kk = n & 63;
  wt[e] = f2bf(w[h * 32768 + d * 64 + kk]);
}

// ---------------------------------------------------------------------------
// K1: Y = X @ Wt^T.  X fp32 (8192x512), Wt bf16 (512x512 row-major [n][d]).
// MODE 0: head-major bf16 out: Y[(h*4+b)*2048+m][dk], scaled by `scale`
// MODE 1: V transposed+k-permuted out: Y[n][pi(i)]  (for direct PV B-frags)
template<int MODE>
__global__ __launch_bounds__(256) void k_proj(const float* __restrict__ X,
                                              const u16* __restrict__ Wt,
                                              u16* __restrict__ Y, float scale){
  __shared__ __align__(16) u16 Xs[64 * 72];
  __shared__ __align__(16) u16 Ws[64 * 72];
  const int t = threadIdx.x;
  const int lane = t & 63, w = t >> 6;
  const int g = lane >> 4, li = lane & 15;
  const int i0 = blockIdx.x * 64;
  const int n0 = blockIdx.y * 64;
  f32x4v acc[4] = {};
  for(int kc = 0; kc < 512; kc += 64){
    __syncthreads();
    #pragma unroll
    for(int it = 0; it < 4; ++it){
      int eidx = it * 256 + t, row = eidx >> 4, q4 = eidx & 15;
      f32x4v xv = *(const f32x4v*)(X + (size_t)(i0 + row) * 512 + kc + q4 * 4);
      u16x4v bv; bv[0]=f2bf(xv[0]); bv[1]=f2bf(xv[1]); bv[2]=f2bf(xv[2]); bv[3]=f2bf(xv[3]);
      *(u16x4v*)(Xs + row * 72 + q4 * 4) = bv;
    }
    #pragma unroll
    for(int it = 0; it < 2; ++it){
      int eidx = it * 256 + t, row = eidx >> 3, c8 = eidx & 7;
      u16x8v wv = *(const u16x8v*)(Wt + (size_t)(n0 + row) * 512 + kc + c8 * 8);
      *(u16x8v*)(Ws + row * 72 + c8 * 8) = wv;
    }
    __syncthreads();
    #pragma unroll
    for(int s = 0; s < 2; ++s){
      int k0 = s * 32 + g * 8;           // contiguous k-bijection (A/B consistent)
      s16x8v a = *(const s16x8v*)(Xs + (w * 16 + li) * 72 + k0);
      #pragma unroll
      for(int j = 0; j < 4; ++j){
        s16x8v b = *(const s16x8v*)(Ws + (j * 16 + li) * 72 + k0);
        acc[j] = mfma16(a, b, acc[j]);
      }
    }
  }
  if(MODE == 0){
    #pragma unroll
    for(int j = 0; j < 4; ++j){
      int n = n0 + j * 16 + li, hh = n >> 6, dk = n & 63;
      #pragma unroll
      for(int r = 0; r < 4; ++r){
        int i = i0 + w * 16 + g * 4 + r, bb = i >> 11, m = i & 2047;
        Y[((size_t)(hh * 4 + bb) * 2048 + m) * 64 + dk] = f2bf(acc[j][r] * scale);
      }
    }
  } else {
    // interleaved-bijection permutation within each 32-row block:
    // pi(m) = (m&~31) | ((m>>2)&3)<<3 | ((m>>4)&1)<<2 | (m&3)
    int ibase = i0 + w * 16 + g * 4;   // multiple of 4
    int pi = (ibase & ~31) | (((ibase >> 2) & 3) << 3) | (((ibase >> 4) & 1) << 2);
    #pragma unroll
    for(int j = 0; j < 4; ++j){
      int n = n0 + j * 16 + li;
      u16x4v pk;
      #pragma unroll
      for(int r = 0; r < 4; ++r) pk[r] = f2bf(acc[j][r]);
      *(u16x4v*)(Y + (size_t)n * 8192 + pi) = pk;
    }
  }
}

// ---------------------------------------------------------------------------
// Attention pass A (k_sum): per-lane sum of exp2(S') over all m; no max needed
// (|S'| <= ~6; exp2 overflow only past 127). Q pre-scaled by log2e/sqrt(512).
// Each wave: 32 q-rows (2 x 16-q B-frags). Software-pipelined K loads.

#define LOADK(B, ht) { \
  const u16* _p = kp + (size_t)(ht) * 2048; \
  B##0 = *(const s16x8v*)(_p); \
  B##1 = *(const s16x8v*)(_p + 32); \
  B##2 = *(const s16x8v*)(_p + 1024); \
  B##3 = *(const s16x8v*)(_p + 1056); }

#define STEPA(B) { \
  f32x4v z0 = {}, z1 = {}; \
  z0 = mfma16(B##0, bq00, z0); z0 = mfma16(B##1, bq01, z0); \
  z1 = mfma16(B##2, bq00, z1); z1 = mfma16(B##3, bq01, z1); \
  _Pragma("unroll") for(int r = 0; r < 4; ++r){ s00[r] += exp2f(z0[r]); s01[r] += exp2f(z1[r]); } \
  f32x4v y0 = {}, y1 = {}; \
  y0 = mfma16(B##0, bq10, y0); y0 = mfma16(B##1, bq11, y0); \
  y1 = mfma16(B##2, bq10, y1); y1 = mfma16(B##3, bq11, y1); \
  _Pragma("unroll") for(int r = 0; r < 4; ++r){ s10[r] += exp2f(y0[r]); s11[r] += exp2f(y1[r]); } }

__global__ __launch_bounds__(256) void k_sum(const u16* __restrict__ QHH, const u16* __restrict__ KHH,
                                             float* __restrict__ Lrcp){
  const int t = threadIdx.x, lane = t & 63, w = t >> 6;
  const int g = lane >> 4, li = lane & 15;
  const int lt = blockIdx.x;                 // 0..15
  const int hb = blockIdx.y;                 // h*4 + b
  const size_t base_hb = (size_t)hb * 2048;
  const int qbase = lt * 128 + w * 32;

  s16x8v bq00, bq01, bq10, bq11;
  {
    const u16* qp0 = QHH + (base_hb + qbase + li) * 64 + g * 8;
    const u16* qp1 = QHH + (base_hb + qbase + 16 + li) * 64 + g * 8;
    bq00 = *(const s16x8v*)(qp0); bq01 = *(const s16x8v*)(qp0 + 32);
    bq10 = *(const s16x8v*)(qp1); bq11 = *(const s16x8v*)(qp1 + 32);
  }
  const u16* kp = KHH + (base_hb + li) * 64 + g * 8;

  f32x4v s00 = {}, s01 = {}, s10 = {}, s11 = {};
  s16x8v kA0, kA1, kA2, kA3, kB0, kB1, kB2, kB3;
  LOADK(kA, 0);
  for(int ht = 0; ht < 62; ht += 2){
    LOADK(kB, ht + 1);
    STEPA(kA);
    LOADK(kA, ht + 2);
    STEPA(kB);
  }
  LOADK(kB, 63);
  STEPA(kA);
  STEPA(kB);

  float l0 = (s00[0]+s00[1]+s00[2]+s00[3]) + (s01[0]+s01[1]+s01[2]+s01[3]);
  float l1 = (s10[0]+s10[1]+s10[2]+s10[3]) + (s11[0]+s11[1]+s11[2]+s11[3]);
  l0 += __shfl_xor(l0, 16, 64); l0 += __shfl_xor(l0, 32, 64);
  l1 += __shfl_xor(l1, 16, 64); l1 += __shfl_xor(l1, 32, 64);
  if(lane < 16){
    Lrcp[base_hb + qbase + lane]      = 1.0f / l0;
    Lrcp[base_hb + qbase + 16 + lane] = 1.0f / l1;
  }
}

// ---------------------------------------------------------------------------
// Attention pass B (k_attn): recompute S', P = exp2(S')*rl, write fp32 ATT
// (nontemporal float4), PV from registers. K and V double-buffered, 2-deep.

#define LOADV(B, ht) { \
  const u16* _p = vp + (ht) * 32; \
  B##0 = *(const s16x8v*)(_p); \
  B##1 = *(const s16x8v*)(_p + 131072); \
  B##2 = *(const s16x8v*)(_p + 262144); \
  B##3 = *(const s16x8v*)(_p + 393216); }

#define QS_HALF(KB, VB, bqa, bqb, rl, qs, ht) { \
  f32x4v z0 = {}, z1 = {}; \
  z0 = mfma16(KB##0, bqa, z0); z0 = mfma16(KB##1, bqb, z0); \
  z1 = mfma16(KB##2, bqa, z1); z1 = mfma16(KB##3, bqb, z1); \
  f32x4v p0, p1; \
  _Pragma("unroll") for(int r = 0; r < 4; ++r){ p0[r] = exp2f(z0[r]) * rl; p1[r] = exp2f(z1[r]) * rl; } \
  float* _ab = attb + (size_t)((qs) * 16 + li) * 2048 + (ht) * 32 + g * 4; \
  __builtin_nontemporal_store(p0, (f32x4v*)(_ab)); \
  __builtin_nontemporal_store(p1, (f32x4v*)(_ab + 16)); \
  union { u16 hh[8]; s16x8v v; } _u; \
  _Pragma("unroll") for(int r = 0; r < 4; ++r){ _u.hh[r] = f2bf(p0[r]); _u.hh[4 + r] = f2bf(p1[r]); } \
  acc##qs##0 = mfma16(_u.v, VB##0, acc##qs##0); \
  acc##qs##1 = mfma16(_u.v, VB##1, acc##qs##1); \
  acc##qs##2 = mfma16(_u.v, VB##2, acc##qs##2); \
  acc##qs##3 = mfma16(_u.v, VB##3, acc##qs##3); }

#define STEPB(KB, VB, ht) { \
  QS_HALF(KB, VB, bq00, bq01, rl0, 0, ht); \
  QS_HALF(KB, VB, bq10, bq11, rl1, 1, ht); }

__global__ __launch_bounds__(256) void k_attn(const u16* __restrict__ QHH, const u16* __restrict__ KHH,
                                              const u16* __restrict__ VTT, const float* __restrict__ Lrcp,
                                              u16* __restrict__ XC, float* __restrict__ ATT){
  const int t = threadIdx.x, lane = t & 63, w = t >> 6;
  const int g = lane >> 4, li = lane & 15;
  const int lt = blockIdx.x;                 // 0..15
  const int hb = blockIdx.y;                 // h*4 + b
  const int h = hb >> 2, b = hb & 3;
  const size_t base_hb = (size_t)hb * 2048;
  const int qbase = lt * 128 + w * 32;

  s16x8v bq00, bq01, bq10, bq11;
  {
    const u16* qp0 = QHH + (base_hb + qbase + li) * 64 + g * 8;
    const u16* qp1 = QHH + (base_hb + qbase + 16 + li) * 64 + g * 8;
    bq00 = *(const s16x8v*)(qp0); bq01 = *(const s16x8v*)(qp0 + 32);
    bq10 = *(const s16x8v*)(qp1); bq11 = *(const s16x8v*)(qp1 + 32);
  }
  const float rl0 = Lrcp[base_hb + qbase + li];
  const float rl1 = Lrcp[base_hb + qbase + 16 + li];
  const u16* kp = KHH + (base_hb + li) * 64 + g * 8;
  const u16* vp = VTT + (size_t)(h * 64 + li) * 8192 + b * 2048 + g * 8;
  float* attb = ATT + (base_hb + qbase) * 2048;

  f32x4v acc00 = {}, acc01 = {}, acc02 = {}, acc03 = {};
  f32x4v acc10 = {}, acc11 = {}, acc12 = {}, acc13 = {};
  s16x8v kA0, kA1, kA2, kA3, kB0, kB1, kB2, kB3;
  s16x8v vA0, vA1, vA2, vA3, vB0, vB1, vB2, vB3;

  LOADK(kA, 0); LOADV(vA, 0);
  for(int ht = 0; ht < 62; ht += 2){
    LOADK(kB, ht + 1); LOADV(vB, ht + 1);
    STEPB(kA, vA, ht);
    LOADK(kA, ht + 2); LOADV(vA, ht + 2);
    STEPB(kB, vB, ht + 1);
  }
  LOADK(kB, 63); LOADV(vB, 63);
  STEPB(kA, vA, 62);
  STEPB(kB, vB, 63);

  #pragma unroll
  for(int r = 0; r < 4; ++r){
    int row0 = qbase + g * 4 + r;
    int row1 = qbase + 16 + g * 4 + r;
    u16* x0 = XC + (size_t)(b * 2048 + row0) * 512 + h * 64 + li;
    u16* x1 = XC + (size_t)(b * 2048 + row1) * 512 + h * 64 + li;
    x0[0]  = f2bf(acc00[r]); x0[16] = f2bf(acc01[r]); x0[32] = f2bf(acc02[r]); x0[48] = f2bf(acc03[r]);
    x1[0]  = f2bf(acc10[r]); x1[16] = f2bf(acc11[r]); x1[32] = f2bf(acc12[r]); x1[48] = f2bf(acc13[r]);
  }
}

// ---------------------------------------------------------------------------
// K3a: Z[i][d] = sum_c Xb[i][c]*proj_w[d][c] + bias[d] + resid[i][d]   (fp32 out)
__global__ __launch_bounds__(256) void k_out_proj(const u16* __restrict__ Xb,
                                                  const float* __restrict__ Wp,
                                                  const float* __restrict__ bias,
                                                  const float* __restrict__ resid,
                                                  float* __restrict__ Z){
  __shared__ __align__(16) u16 Xs[64 * 72];
  __shared__ __align__(16) u16 Ws[64 * 72];
  const int t = threadIdx.x;
  const int lane = t & 63, w = t >> 6;
  const int g = lane >> 4, li = lane & 15;
  const int i0 = blockIdx.x * 64;
  const int n0 = blockIdx.y * 64;
  f32x4v acc[4] = {};
  for(int kc = 0; kc < 512; kc += 64){
    __syncthreads();
    #pragma unroll
    for(int it = 0; it < 2; ++it){
      int eidx = it * 256 + t, row = eidx >> 3, c8 = eidx & 7;
      u16x8v xv = *(const u16x8v*)(Xb + (size_t)(i0 + row) * 512 + kc + c8 * 8);
      *(u16x8v*)(Xs + row * 72 + c8 * 8) = xv;
    }
    #pragma unroll
    for(int it = 0; it < 4; ++it){
      int eidx = it * 256 + t, row = eidx >> 4, q4 = eidx & 15;
      f32x4v wv = *(const f32x4v*)(Wp + (size_t)(n0 + row) * 512 + kc + q4 * 4);
      u16x4v bv; bv[0]=f2bf(wv[0]); bv[1]=f2bf(wv[1]); bv[2]=f2bf(wv[2]); bv[3]=f2bf(wv[3]);
      *(u16x4v*)(Ws + row * 72 + q4 * 4) = bv;
    }
    __syncthreads();
    #pragma unroll
    for(int s = 0; s < 2; ++s){
      int k0 = s * 32 + g * 8;
      s16x8v a = *(const s16x8v*)(Xs + (w * 16 + li) * 72 + k0);
      #pragma unroll
      for(int j = 0; j < 4; ++j){
        s16x8v b = *(const s16x8v*)(Ws + (j * 16 + li) * 72 + k0);
        acc[j] = mfma16(a, b, acc[j]);
      }
    }
  }
  #pragma unroll
  for(int j = 0; j < 4; ++j)
    #pragma unroll
    for(int r = 0; r < 4; ++r){
      int row = i0 + w * 16 + g * 4 + r;
      int col = n0 + j * 16 + li;
      Z[(size_t)row * 512 + col] = acc[j][r] + bias[col] + resid[(size_t)row * 512 + col];
    }
}

// ---------------------------------------------------------------------------
// K3b: row LayerNorm, torch semantics: (z-mu)/(std_ddof1 + eps)*a2 + b2
__global__ __launch_bounds__(256) void k_ln(const float* __restrict__ Z,
                                            const float* __restrict__ a2,
                                            const float* __restrict__ b2,
                                            float* __restrict__ out){
  __shared__ float red[8];
  const int i = blockIdx.x, t = threadIdx.x;
  const float* z = Z + (size_t)i * 512;
  f32x2v v = *(const f32x2v*)(z + t * 2);
  float s = v[0] + v[1], sq = v[0] * v[0] + v[1] * v[1];
  #pragma unroll
  for(int off = 1; off < 64; off <<= 1){
    s  += __shfl_xor(s,  off, 64);
    sq += __shfl_xor(sq, off, 64);
  }
  const int wid = t >> 6;
  if((t & 63) == 0){ red[wid] = s; red[4 + wid] = sq; }
  __syncthreads();
  float S  = red[0] + red[1] + red[2] + red[3];
  float SQ = red[4] + red[5] + red[6] + red[7];
  float mu = S * (1.0f / 512.0f);
  float var = (SQ - 512.0f * mu * mu) * (1.0f / 511.0f);
  float sigma = sqrtf(fmaxf(var, 0.0f));
  float rs = 1.0f / (sigma + 1e-3f);
  f32x2v o;
  o[0] = (v[0] - mu) * rs * a2[t * 2]     + b2[t * 2];
  o[1] = (v[1] - mu) * rs * a2[t * 2 + 1] + b2[t * 2 + 1];
  *(f32x2v*)(out + (size_t)i * 512 + t * 2) = o;
}

// ---------------------------------------------------------------------------
extern "C" void kernel_launch(void* const* d_in, const int* in_sizes, int n_in,
                              void* d_out, int out_size, void* d_ws, size_t ws_size,
                              hipStream_t stream){
  const float* q      = (const float*)d_in[0];
  const float* k      = (const float*)d_in[1];
  const float* v      = (const float*)d_in[2];
  const float* w_qs   = (const float*)d_in[3];
  const float* w_ks   = (const float*)d_in[4];
  const float* w_vs   = (const float*)d_in[5];
  const float* proj_w = (const float*)d_in[6];
  const float* proj_b = (const float*)d_in[7];
  const float* a2     = (const float*)d_in[8];
  const float* b2     = (const float*)d_in[9];

  char* ws = (char*)d_ws;
  u16* wt    = (u16*)(ws);                       // 1.5 MB (dead after projections)
  u16* qhh   = (u16*)(ws + 1572864);             // 8 MB, head-major, scaled by log2e/sqrt(512)
  u16* khh   = (u16*)(ws + 9961472);             // 8 MB, head-major
  u16* vtt   = (u16*)(ws + 18350080);            // 8 MB, [n=h*64+dv][pi(i)]
  u16* xc    = (u16*)(ws + 26738688);            // 8 MB, row-major [i][512]
  float* zbuf= (float*)(ws + 35127296);          // 16 MB
  float* lrcp= (float*)(ws);                     // 256 KB, reuses dead wt region

  float* out = (float*)d_out;                    // (4,2048,512) fp32
  float* att = out + 4194304;                    // (32,2048,2048) fp32

  // fold 1/sqrt(512) * log2(e) into Q so softmax uses native exp2
  const float qscale = 0.06375872032774575f;

  k_wt<<<dim3(1024), 256, 0, stream>>>(w_qs, wt);
  k_wt<<<dim3(1024), 256, 0, stream>>>(w_ks, wt + 262144);
  k_wt<<<dim3(1024), 256, 0, stream>>>(w_vs, wt + 524288);

  k_proj<0><<<dim3(128, 8), 256, 0, stream>>>(q, wt,          qhh, qscale);
  k_proj<0><<<dim3(128, 8), 256, 0, stream>>>(k, wt + 262144, khh, 1.0f);
  k_proj<1><<<dim3(128, 8), 256, 0, stream>>>(v, wt + 524288, vtt, 1.0f);

  k_sum <<<dim3(16, 32), 256, 0, stream>>>(qhh, khh, lrcp);
  k_attn<<<dim3(16, 32), 256, 0, stream>>>(qhh, khh, vtt, lrcp, xc, att);

  k_out_proj<<<dim3(128, 8), 256, 0, stream>>>(xc, proj_w, proj_b, q, zbuf);
  k_ln<<<dim3(8192), 256, 0, stream>>>(zbuf, a2, b2, out);
}

// Round 4
// 323.694 us; speedup vs baseline: 1.6682x; 1.0240x over previous
//
#include <hip/hip_runtime.h>
#include <stdint.h>

typedef unsigned short u16;
typedef u16   u16x4v __attribute__((ext_vector_type(4)));
typedef u16   u16x8v __attribute__((ext_vector_type(8)));
typedef short s16x8v __attribute__((ext_vector_type(8)));
typedef float f32x4v __attribute__((ext_vector_type(4)));

#define DEV static __device__ __forceinline__

// fp32 -> bf16 round-to-nearest-even
DEV u16 f2bf(float f){
  union { float f; unsigned u; } v; v.f = f;
  unsigned r = v.u + 0x7FFFu + ((v.u >> 16) & 1u);
  return (u16)(r >> 16);
}

DEV f32x4v mfma16(s16x8v a, s16x8v b, f32x4v c){
  return __builtin_amdgcn_mfma_f32_16x16x32_bf16(a, b, c, 0, 0, 0);
}

// ---------------------------------------------------------------------------
// K0: w (8,512,64) fp32 -> wt[n=h*64+kk][d] bf16, optional scale (folds qscale)
__global__ __launch_bounds__(256) void k_wt(const float* __restrict__ w, u16* __restrict__ wt,
                                            float scale){
  int e = blockIdx.x * 256 + threadIdx.x;     // = n*512 + d
  int n = e >> 9, d = e & 511;
  int h = n >> 6, kk = n & 63;
  wt[e] = f2bf(w[h * 32768 + d * 64 + kk] * scale);
}

// K0b: proj_w (512,512) fp32 -> bf16 (no transpose; already [out][in])
__global__ __launch_bounds__(256) void k_wtp(const float* __restrict__ w, u16* __restrict__ wt){
  int e = blockIdx.x * 256 + threadIdx.x;
  wt[e] = f2bf(w[e]);
}

// ---------------------------------------------------------------------------
// Projection family: 32-row i-tile per block, 512 threads (8 waves), each wave
// owns 64 output cols. A-tile staged once in LDS (stride 520 -> conflict-free
// b128 reads). B-frags streamed from L2.
// MODE 0: X fp32 -> Y bf16 head-major  [(h*4+b)*2048+m][dk]
// MODE 1: X fp32 -> Y bf16 vtt         [n][i0 + g*8 + qh*4 + r]  (PV-ready)
// MODE 2: X bf16 (xc) -> out fp32 with +bias +resid, fused LayerNorm
template<int MODE>
__global__ __launch_bounds__(512) void k_proj(const void* __restrict__ Xv,
                                              const u16* __restrict__ Wt,
                                              void* __restrict__ Yv,
                                              const float* __restrict__ bias,
                                              const float* __restrict__ resid,
                                              const float* __restrict__ a2,
                                              const float* __restrict__ b2){
  __shared__ __align__(16) u16 Xs[32 * 520];
  __shared__ float sred[8][32], sqred[8][32], muL[32], rsL[32];
  const int t = threadIdx.x;
  const int lane = t & 63, w = t >> 6;          // w = wave 0..7
  const int g = lane >> 4, li = lane & 15;
  const int i0 = blockIdx.x * 32;
  const int n0 = w * 64;

  // ---- stage A tile ----
  if(MODE == 2){
    const u16* X = (const u16*)Xv;
    #pragma unroll
    for(int it = 0; it < 4; ++it){
      int s = it * 512 + t, row = s >> 6, c8 = s & 63;
      u16x8v xv = *(const u16x8v*)(X + (size_t)(i0 + row) * 512 + c8 * 8);
      *(u16x8v*)(Xs + row * 520 + c8 * 8) = xv;
    }
  } else {
    const float* X = (const float*)Xv;
    #pragma unroll
    for(int it = 0; it < 8; ++it){
      int s = it * 512 + t, row = s >> 7, c4 = s & 127;
      f32x4v xv = *(const f32x4v*)(X + (size_t)(i0 + row) * 512 + c4 * 4);
      u16x4v bv; bv[0]=f2bf(xv[0]); bv[1]=f2bf(xv[1]); bv[2]=f2bf(xv[2]); bv[3]=f2bf(xv[3]);
      *(u16x4v*)(Xs + row * 520 + c4 * 4) = bv;
    }
  }
  __syncthreads();

  // ---- MFMA main loop: K=512 in 16 chunks of 32 ----
  f32x4v acc[2][4] = {};
  #pragma unroll 4
  for(int c = 0; c < 16; ++c){
    int k0 = c * 32 + g * 8;
    s16x8v a0 = *(const s16x8v*)(Xs + li * 520 + k0);
    s16x8v a1 = *(const s16x8v*)(Xs + (16 + li) * 520 + k0);
    #pragma unroll
    for(int j = 0; j < 4; ++j){
      s16x8v b = *(const s16x8v*)(Wt + (size_t)(n0 + j * 16 + li) * 512 + k0);
      acc[0][j] = mfma16(a0, b, acc[0][j]);
      acc[1][j] = mfma16(a1, b, acc[1][j]);
    }
  }

  // ---- epilogues ----
  if(MODE == 0){
    u16* Y = (u16*)Yv;                      // h == w
    #pragma unroll
    for(int qh = 0; qh < 2; ++qh)
      #pragma unroll
      for(int j = 0; j < 4; ++j)
        #pragma unroll
        for(int r = 0; r < 4; ++r){
          int i = i0 + qh * 16 + g * 4 + r, bb = i >> 11, m = i & 2047;
          Y[((size_t)(w * 4 + bb) * 2048 + m) * 64 + j * 16 + li] = f2bf(acc[qh][j][r]);
        }
  } else if(MODE == 1){
    u16* Y = (u16*)Yv;
    #pragma unroll
    for(int qh = 0; qh < 2; ++qh)
      #pragma unroll
      for(int j = 0; j < 4; ++j){
        u16x4v pk;
        #pragma unroll
        for(int r = 0; r < 4; ++r) pk[r] = f2bf(acc[qh][j][r]);
        int n = n0 + j * 16 + li;
        *(u16x4v*)((u16*)Yv + (size_t)n * 8192 + i0 + g * 8 + qh * 4) = pk;
      }
  } else {
    float* Yf = (float*)Yv;
    float biasv[4], a2v[4], b2v[4];
    #pragma unroll
    for(int j = 0; j < 4; ++j){
      int n = n0 + j * 16 + li;
      biasv[j] = bias[n]; a2v[j] = a2[n]; b2v[j] = b2[n];
    }
    float zres[2][4][4];
    #pragma unroll
    for(int qh = 0; qh < 2; ++qh)
      #pragma unroll
      for(int j = 0; j < 4; ++j){
        int n = n0 + j * 16 + li;
        #pragma unroll
        for(int r = 0; r < 4; ++r){
          int i = i0 + qh * 16 + g * 4 + r;
          zres[qh][j][r] = acc[qh][j][r] + biasv[j] + resid[(size_t)i * 512 + n];
        }
      }
    #pragma unroll
    for(int qh = 0; qh < 2; ++qh)
      #pragma unroll
      for(int r = 0; r < 4; ++r){
        float S = 0.f, SQ = 0.f;
        #pragma unroll
        for(int j = 0; j < 4; ++j){ float zz = zres[qh][j][r]; S += zz; SQ += zz * zz; }
        #pragma unroll
        for(int off = 1; off < 16; off <<= 1){ S += __shfl_xor(S, off, 16); SQ += __shfl_xor(SQ, off, 16); }
        if(li == 0){ sred[w][qh * 16 + g * 4 + r] = S; sqred[w][qh * 16 + g * 4 + r] = SQ; }
      }
    __syncthreads();
    if(t < 32){
      float S = 0.f, SQ = 0.f;
      #pragma unroll
      for(int ww = 0; ww < 8; ++ww){ S += sred[ww][t]; SQ += sqred[ww][t]; }
      float mu = S * (1.0f / 512.0f);
      float var = (SQ - 512.0f * mu * mu) * (1.0f / 511.0f);
      muL[t] = mu;
      rsL[t] = 1.0f / (sqrtf(fmaxf(var, 0.0f)) + 1e-3f);
    }
    __syncthreads();
    #pragma unroll
    for(int qh = 0; qh < 2; ++qh)
      #pragma unroll
      for(int r = 0; r < 4; ++r){
        int rloc = qh * 16 + g * 4 + r;
        float mu = muL[rloc], rs = rsL[rloc];
        size_t ib = (size_t)(i0 + rloc) * 512;
        #pragma unroll
        for(int j = 0; j < 4; ++j)
          Yf[ib + n0 + j * 16 + li] = (zres[qh][j][r] - mu) * rs * a2v[j] + b2v[j];
      }
  }
}

// ---------------------------------------------------------------------------
// Merged attention: pass A (exp2-sum) + pass B (recompute, write ATT, PV).
// No LDS, no barriers; 2-deep software pipeline; XCD-swizzled block ids.

#define LOADK(B, ht) { \
  const u16* _p = kp + (size_t)(ht) * 2048; \
  B##0 = *(const s16x8v*)(_p); \
  B##1 = *(const s16x8v*)(_p + 32); \
  B##2 = *(const s16x8v*)(_p + 1024); \
  B##3 = *(const s16x8v*)(_p + 1056); }

#define STEPA(B) { \
  f32x4v z0 = {}, z1 = {}; \
  z0 = mfma16(B##0, bq00, z0); z0 = mfma16(B##1, bq01, z0); \
  z1 = mfma16(B##2, bq00, z1); z1 = mfma16(B##3, bq01, z1); \
  _Pragma("unroll") for(int r = 0; r < 4; ++r){ s00[r] += exp2f(z0[r]); s01[r] += exp2f(z1[r]); } \
  f32x4v y0 = {}, y1 = {}; \
  y0 = mfma16(B##0, bq10, y0); y0 = mfma16(B##1, bq11, y0); \
  y1 = mfma16(B##2, bq10, y1); y1 = mfma16(B##3, bq11, y1); \
  _Pragma("unroll") for(int r = 0; r < 4; ++r){ s10[r] += exp2f(y0[r]); s11[r] += exp2f(y1[r]); } }

#define LOADV(B, ht) { \
  const u16* _p = vp + (ht) * 32; \
  B##0 = *(const s16x8v*)(_p); \
  B##1 = *(const s16x8v*)(_p + 131072); \
  B##2 = *(const s16x8v*)(_p + 262144); \
  B##3 = *(const s16x8v*)(_p + 393216); }

#define QS_HALF(KB, VB, bqa, bqb, rl, qs, ht) { \
  f32x4v z0 = {}, z1 = {}; \
  z0 = mfma16(KB##0, bqa, z0); z0 = mfma16(KB##1, bqb, z0); \
  z1 = mfma16(KB##2, bqa, z1); z1 = mfma16(KB##3, bqb, z1); \
  f32x4v p0, p1; \
  _Pragma("unroll") for(int r = 0; r < 4; ++r){ p0[r] = exp2f(z0[r]) * rl; p1[r] = exp2f(z1[r]) * rl; } \
  float* _ab = attb + (size_t)((qs) * 16 + li) * 2048 + (ht) * 32 + g * 4; \
  __builtin_nontemporal_store(p0, (f32x4v*)(_ab)); \
  __builtin_nontemporal_store(p1, (f32x4v*)(_ab + 16)); \
  union { u16 hh[8]; s16x8v v; } _u; \
  _Pragma("unroll") for(int r = 0; r < 4; ++r){ _u.hh[r] = f2bf(p0[r]); _u.hh[4 + r] = f2bf(p1[r]); } \
  acc##qs##0 = mfma16(_u.v, VB##0, acc##qs##0); \
  acc##qs##1 = mfma16(_u.v, VB##1, acc##qs##1); \
  acc##qs##2 = mfma16(_u.v, VB##2, acc##qs##2); \
  acc##qs##3 = mfma16(_u.v, VB##3, acc##qs##3); }

#define STEPB(KB, VB, ht) { \
  QS_HALF(KB, VB, bq00, bq01, rl0, 0, ht); \
  QS_HALF(KB, VB, bq10, bq11, rl1, 1, ht); }

__global__ __launch_bounds__(256) void k_attn(const u16* __restrict__ QHH, const u16* __restrict__ KHH,
                                              const u16* __restrict__ VTT,
                                              u16* __restrict__ XC, float* __restrict__ ATT){
  const int t = threadIdx.x, lane = t & 63, w = t >> 6;
  const int g = lane >> 4, li = lane & 15;
  // XCD swizzle: all 16 q-tiles of an hb on one XCD; 4 hb per XCD (2MB K+V in L2)
  const int gid = blockIdx.x;                // 0..511
  const int xcd = gid & 7, rem = gid >> 3;
  const int lt = rem & 15;
  const int hb = xcd * 4 + (rem >> 4);
  const int h = hb >> 2, b = hb & 3;
  const size_t base_hb = (size_t)hb * 2048;
  const int qbase = lt * 128 + w * 32;

  s16x8v bq00, bq01, bq10, bq11;
  {
    const u16* qp0 = QHH + (base_hb + qbase + li) * 64 + g * 8;
    const u16* qp1 = QHH + (base_hb + qbase + 16 + li) * 64 + g * 8;
    bq00 = *(const s16x8v*)(qp0); bq01 = *(const s16x8v*)(qp0 + 32);
    bq10 = *(const s16x8v*)(qp1); bq11 = *(const s16x8v*)(qp1 + 32);
  }
  const u16* kp = KHH + (base_hb + li) * 64 + g * 8;
  const u16* vp = VTT + (size_t)(h * 64 + li) * 8192 + b * 2048 + g * 8;

  // ---- pass A: per-lane exp2 sums ----
  f32x4v s00 = {}, s01 = {}, s10 = {}, s11 = {};
  {
    s16x8v kA0, kA1, kA2, kA3, kB0, kB1, kB2, kB3;
    LOADK(kA, 0);
    for(int ht = 0; ht < 62; ht += 2){
      LOADK(kB, ht + 1);
      STEPA(kA);
      LOADK(kA, ht + 2);
      STEPA(kB);
    }
    LOADK(kB, 63);
    STEPA(kA);
    STEPA(kB);
  }
  float l0 = (s00[0]+s00[1]+s00[2]+s00[3]) + (s01[0]+s01[1]+s01[2]+s01[3]);
  float l1 = (s10[0]+s10[1]+s10[2]+s10[3]) + (s11[0]+s11[1]+s11[2]+s11[3]);
  l0 += __shfl_xor(l0, 16, 64); l0 += __shfl_xor(l0, 32, 64);
  l1 += __shfl_xor(l1, 16, 64); l1 += __shfl_xor(l1, 32, 64);
  const float rl0 = 1.0f / l0;
  const float rl1 = 1.0f / l1;

  // ---- pass B ----
  float* attb = ATT + (base_hb + qbase) * 2048;
  f32x4v acc00 = {}, acc01 = {}, acc02 = {}, acc03 = {};
  f32x4v acc10 = {}, acc11 = {}, acc12 = {}, acc13 = {};
  {
    s16x8v kA0, kA1, kA2, kA3, kB0, kB1, kB2, kB3;
    s16x8v vA0, vA1, vA2, vA3, vB0, vB1, vB2, vB3;
    LOADK(kA, 0); LOADV(vA, 0);
    for(int ht = 0; ht < 62; ht += 2){
      LOADK(kB, ht + 1); LOADV(vB, ht + 1);
      STEPB(kA, vA, ht);
      LOADK(kA, ht + 2); LOADV(vA, ht + 2);
      STEPB(kB, vB, ht + 1);
    }
    LOADK(kB, 63); LOADV(vB, 63);
    STEPB(kA, vA, 62);
    STEPB(kB, vB, 63);
  }

  #pragma unroll
  for(int r = 0; r < 4; ++r){
    int row0 = qbase + g * 4 + r;
    int row1 = qbase + 16 + g * 4 + r;
    u16* x0 = XC + (size_t)(b * 2048 + row0) * 512 + h * 64 + li;
    u16* x1 = XC + (size_t)(b * 2048 + row1) * 512 + h * 64 + li;
    x0[0]  = f2bf(acc00[r]); x0[16] = f2bf(acc01[r]); x0[32] = f2bf(acc02[r]); x0[48] = f2bf(acc03[r]);
    x1[0]  = f2bf(acc10[r]); x1[16] = f2bf(acc11[r]); x1[32] = f2bf(acc12[r]); x1[48] = f2bf(acc13[r]);
  }
}

// ---------------------------------------------------------------------------
extern "C" void kernel_launch(void* const* d_in, const int* in_sizes, int n_in,
                              void* d_out, int out_size, void* d_ws, size_t ws_size,
                              hipStream_t stream){
  const float* q      = (const float*)d_in[0];
  const float* k      = (const float*)d_in[1];
  const float* v      = (const float*)d_in[2];
  const float* w_qs   = (const float*)d_in[3];
  const float* w_ks   = (const float*)d_in[4];
  const float* w_vs   = (const float*)d_in[5];
  const float* proj_w = (const float*)d_in[6];
  const float* proj_b = (const float*)d_in[7];
  const float* a2     = (const float*)d_in[8];
  const float* b2     = (const float*)d_in[9];

  char* ws = (char*)d_ws;
  u16* wt    = (u16*)(ws);                       // 3 x 512KB (q-weights pre-scaled)
  u16* wtp   = (u16*)(ws + 1572864);             // 512KB proj_w bf16
  u16* qhh   = (u16*)(ws + 2097152);             // 8 MB head-major
  u16* khh   = (u16*)(ws + 10485760);            // 8 MB head-major
  u16* vtt   = (u16*)(ws + 18874368);            // 8 MB [n][perm(i)]
  u16* xc    = (u16*)(ws + 27262976);            // 8 MB [i][512]

  float* out = (float*)d_out;                    // (4,2048,512) fp32
  float* att = out + 4194304;                    // (32,2048,2048) fp32

  // fold 1/sqrt(512) * log2(e) into the Q projection weights
  const float qscale = 0.06375872032774575f;

  k_wt <<<dim3(1024), 256, 0, stream>>>(w_qs, wt,          qscale);
  k_wt <<<dim3(1024), 256, 0, stream>>>(w_ks, wt + 262144, 1.0f);
  k_wt <<<dim3(1024), 256, 0, stream>>>(w_vs, wt + 524288, 1.0f);
  k_wtp<<<dim3(1024), 256, 0, stream>>>(proj_w, wtp);

  k_proj<0><<<dim3(256), 512, 0, stream>>>(q, wt,          qhh, nullptr, nullptr, nullptr, nullptr);
  k_proj<0><<<dim3(256), 512, 0, stream>>>(k, wt + 262144, khh, nullptr, nullptr, nullptr, nullptr);
  k_proj<1><<<dim3(256), 512, 0, stream>>>(v, wt + 524288, vtt, nullptr, nullptr, nullptr, nullptr);

  k_attn<<<dim3(512), 256, 0, stream>>>(qhh, khh, vtt, xc, att);

  k_proj<2><<<dim3(256), 512, 0, stream>>>(xc, wtp, out, proj_b, q, a2, b2);
}

// Round 6
// 318.699 us; speedup vs baseline: 1.6943x; 1.0157x over previous
//
#include <hip/hip_runtime.h>
#include <stdint.h>

typedef unsigned short u16;
typedef u16   u16x4v __attribute__((ext_vector_type(4)));
typedef u16   u16x8v __attribute__((ext_vector_type(8)));
typedef short s16x8v __attribute__((ext_vector_type(8)));
typedef float f32x4v __attribute__((ext_vector_type(4)));

#define DEV static __device__ __forceinline__

// fp32 -> bf16 round-to-nearest-even (scalar)
DEV u16 f2bf(float f){
  union { float f; unsigned u; } v; v.f = f;
  unsigned r = v.u + 0x7FFFu + ((v.u >> 16) & 1u);
  return (u16)(r >> 16);
}

DEV f32x4v mfma16(s16x8v a, s16x8v b, f32x4v c){
  return __builtin_amdgcn_mfma_f32_16x16x32_bf16(a, b, c, 0, 0, 0);
}

// ---------------------------------------------------------------------------
// k_wall: all weight prep in one launch.
// tsel 0..2: w (8,512,64) fp32 -> wt[tsel*512 + h*64+kk][d] bf16 (q scaled)
// tsel 3:    proj_w (512,512) fp32 -> wtp bf16
__global__ __launch_bounds__(256) void k_wall(const float* __restrict__ w_qs,
                                              const float* __restrict__ w_ks,
                                              const float* __restrict__ w_vs,
                                              const float* __restrict__ proj_w,
                                              u16* __restrict__ wt, u16* __restrict__ wtp,
                                              float qscale){
  int gid = blockIdx.x;
  int tsel = gid >> 10;
  int e = (gid & 1023) * 256 + threadIdx.x;
  if(tsel == 3){
    wtp[e] = f2bf(proj_w[e]);
  } else {
    const float* w = tsel == 0 ? w_qs : (tsel == 1 ? w_ks : w_vs);
    float sc = tsel == 0 ? qscale : 1.0f;
    int n = e >> 9, d = e & 511;
    int h = n >> 6, kk = n & 63;
    wt[tsel * 262144 + n * 512 + d] = f2bf(w[h * 32768 + d * 64 + kk] * sc);
  }
}

// ---------------------------------------------------------------------------
// Fused QKV projection. Grid (256 i-tiles, 6 col-tiles), 256 threads (4 waves).
// Tile: 32 rows x 256 cols; wave owns 64 cols. W double-buffered in registers.
// y>>1 selects tensor (0=q,1=k,2=v); epilogue: head-major (q,k) / vtt (v).
__global__ __launch_bounds__(256) void k_qkv(const float* __restrict__ Q,
                                             const float* __restrict__ K,
                                             const float* __restrict__ V,
                                             const u16* __restrict__ Wt,
                                             u16* __restrict__ qhh, u16* __restrict__ khh,
                                             u16* __restrict__ vtt){
  __shared__ __align__(16) u16 Xs[32 * 520];
  const int t = threadIdx.x;
  const int lane = t & 63, w = t >> 6;          // wave 0..3
  const int g = lane >> 4, li = lane & 15;
  const int i0 = blockIdx.x * 32;
  const int y = blockIdx.y;
  const int tsel = y >> 1;
  const float* X = tsel == 0 ? Q : (tsel == 1 ? K : V);
  const int n0 = (y & 1) * 256 + w * 64;        // col base within tensor

  // stage X tile (32 x 512 fp32 -> bf16)
  #pragma unroll
  for(int it = 0; it < 16; ++it){
    int s = it * 256 + t, row = s >> 7, c4 = s & 127;
    f32x4v xv = *(const f32x4v*)(X + (size_t)(i0 + row) * 512 + c4 * 4);
    u16x4v bv; bv[0]=f2bf(xv[0]); bv[1]=f2bf(xv[1]); bv[2]=f2bf(xv[2]); bv[3]=f2bf(xv[3]);
    *(u16x4v*)(Xs + row * 520 + c4 * 4) = bv;
  }
  __syncthreads();

  const int wbase = tsel * 512 + n0;
  const u16* wp0 = Wt + (size_t)(wbase +  0 + li) * 512 + g * 8;
  const u16* wp1 = Wt + (size_t)(wbase + 16 + li) * 512 + g * 8;
  const u16* wp2 = Wt + (size_t)(wbase + 32 + li) * 512 + g * 8;
  const u16* wp3 = Wt + (size_t)(wbase + 48 + li) * 512 + g * 8;

#define LOADW(S, c) { \
  S##0 = *(const s16x8v*)(wp0 + (c) * 32); \
  S##1 = *(const s16x8v*)(wp1 + (c) * 32); \
  S##2 = *(const s16x8v*)(wp2 + (c) * 32); \
  S##3 = *(const s16x8v*)(wp3 + (c) * 32); }
#define COMPW(S, c) { \
  int k0 = (c) * 32 + g * 8; \
  s16x8v a0 = *(const s16x8v*)(Xs + li * 520 + k0); \
  s16x8v a1 = *(const s16x8v*)(Xs + (16 + li) * 520 + k0); \
  acc[0][0] = mfma16(a0, S##0, acc[0][0]); acc[1][0] = mfma16(a1, S##0, acc[1][0]); \
  acc[0][1] = mfma16(a0, S##1, acc[0][1]); acc[1][1] = mfma16(a1, S##1, acc[1][1]); \
  acc[0][2] = mfma16(a0, S##2, acc[0][2]); acc[1][2] = mfma16(a1, S##2, acc[1][2]); \
  acc[0][3] = mfma16(a0, S##3, acc[0][3]); acc[1][3] = mfma16(a1, S##3, acc[1][3]); }

  f32x4v acc[2][4] = {};
  s16x8v wA0, wA1, wA2, wA3, wB0, wB1, wB2, wB3;
  LOADW(wA, 0);
  #pragma unroll
  for(int c = 0; c < 16; c += 2){
    LOADW(wB, c + 1);
    COMPW(wA, c);
    if(c + 2 < 16) LOADW(wA, c + 2);
    COMPW(wB, c + 1);
  }
#undef LOADW
#undef COMPW

  if(tsel < 2){
    u16* Y = tsel == 0 ? qhh : khh;
    #pragma unroll
    for(int rg = 0; rg < 2; ++rg)
      #pragma unroll
      for(int j = 0; j < 4; ++j){
        int n = n0 + j * 16 + li, h = n >> 6, dk = n & 63;
        #pragma unroll
        for(int r = 0; r < 4; ++r){
          int i = i0 + rg * 16 + g * 4 + r, bb = i >> 11, m = i & 2047;
          Y[((size_t)(h * 4 + bb) * 2048 + m) * 64 + dk] = f2bf(acc[rg][j][r]);
        }
      }
  } else {
    #pragma unroll
    for(int rg = 0; rg < 2; ++rg)
      #pragma unroll
      for(int j = 0; j < 4; ++j){
        int n = n0 + j * 16 + li;
        u16x4v pk;
        #pragma unroll
        for(int r = 0; r < 4; ++r) pk[r] = f2bf(acc[rg][j][r]);
        *(u16x4v*)(vtt + (size_t)n * 8192 + i0 + g * 8 + rg * 4) = pk;
      }
  }
}

// ---------------------------------------------------------------------------
// Merged attention: pass A (exp2-sum) + pass B (recompute, write ATT, PV).
// No LDS, no barriers; 2-deep software pipeline; XCD-swizzled block ids.

#define LOADK(B, ht) { \
  const u16* _p = kp + (size_t)(ht) * 2048; \
  B##0 = *(const s16x8v*)(_p); \
  B##1 = *(const s16x8v*)(_p + 32); \
  B##2 = *(const s16x8v*)(_p + 1024); \
  B##3 = *(const s16x8v*)(_p + 1056); }

#define STEPA(B) { \
  f32x4v z0 = {}, z1 = {}; \
  z0 = mfma16(B##0, bq00, z0); z0 = mfma16(B##1, bq01, z0); \
  z1 = mfma16(B##2, bq00, z1); z1 = mfma16(B##3, bq01, z1); \
  _Pragma("unroll") for(int r = 0; r < 4; ++r){ s00[r] += exp2f(z0[r]); s01[r] += exp2f(z1[r]); } \
  f32x4v y0 = {}, y1 = {}; \
  y0 = mfma16(B##0, bq10, y0); y0 = mfma16(B##1, bq11, y0); \
  y1 = mfma16(B##2, bq10, y1); y1 = mfma16(B##3, bq11, y1); \
  _Pragma("unroll") for(int r = 0; r < 4; ++r){ s10[r] += exp2f(y0[r]); s11[r] += exp2f(y1[r]); } }

#define LOADV(B, ht) { \
  const u16* _p = vp + (ht) * 32; \
  B##0 = *(const s16x8v*)(_p); \
  B##1 = *(const s16x8v*)(_p + 131072); \
  B##2 = *(const s16x8v*)(_p + 262144); \
  B##3 = *(const s16x8v*)(_p + 393216); }

#define QS_HALF(KB, VB, bqa, bqb, rl, qs, ht) { \
  f32x4v z0 = {}, z1 = {}; \
  z0 = mfma16(KB##0, bqa, z0); z0 = mfma16(KB##1, bqb, z0); \
  z1 = mfma16(KB##2, bqa, z1); z1 = mfma16(KB##3, bqb, z1); \
  f32x4v p0, p1; \
  _Pragma("unroll") for(int r = 0; r < 4; ++r){ p0[r] = exp2f(z0[r]) * rl; p1[r] = exp2f(z1[r]) * rl; } \
  float* _ab = attb + (size_t)((qs) * 16 + li) * 2048 + (ht) * 32 + g * 4; \
  __builtin_nontemporal_store(p0, (f32x4v*)(_ab)); \
  __builtin_nontemporal_store(p1, (f32x4v*)(_ab + 16)); \
  union { u16 hh[8]; s16x8v v; } _u; \
  _Pragma("unroll") for(int r = 0; r < 4; ++r){ _u.hh[r] = f2bf(p0[r]); _u.hh[4 + r] = f2bf(p1[r]); } \
  acc##qs##0 = mfma16(_u.v, VB##0, acc##qs##0); \
  acc##qs##1 = mfma16(_u.v, VB##1, acc##qs##1); \
  acc##qs##2 = mfma16(_u.v, VB##2, acc##qs##2); \
  acc##qs##3 = mfma16(_u.v, VB##3, acc##qs##3); }

#define STEPB(KB, VB, ht) { \
  QS_HALF(KB, VB, bq00, bq01, rl0, 0, ht); \
  QS_HALF(KB, VB, bq10, bq11, rl1, 1, ht); }

__global__ __launch_bounds__(256) void k_attn(const u16* __restrict__ QHH, const u16* __restrict__ KHH,
                                              const u16* __restrict__ VTT,
                                              u16* __restrict__ XC, float* __restrict__ ATT){
  const int t = threadIdx.x, lane = t & 63, w = t >> 6;
  const int g = lane >> 4, li = lane & 15;
  // XCD swizzle: all 16 q-tiles of an hb on one XCD; 4 hb per XCD (2MB K+V in L2)
  const int gid = blockIdx.x;                // 0..511
  const int xcd = gid & 7, rem = gid >> 3;
  const int lt = rem & 15;
  const int hb = xcd * 4 + (rem >> 4);
  const int h = hb >> 2, b = hb & 3;
  const size_t base_hb = (size_t)hb * 2048;
  const int qbase = lt * 128 + w * 32;

  s16x8v bq00, bq01, bq10, bq11;
  {
    const u16* qp0 = QHH + (base_hb + qbase + li) * 64 + g * 8;
    const u16* qp1 = QHH + (base_hb + qbase + 16 + li) * 64 + g * 8;
    bq00 = *(const s16x8v*)(qp0); bq01 = *(const s16x8v*)(qp0 + 32);
    bq10 = *(const s16x8v*)(qp1); bq11 = *(const s16x8v*)(qp1 + 32);
  }
  const u16* kp = KHH + (base_hb + li) * 64 + g * 8;
  const u16* vp = VTT + (size_t)(h * 64 + li) * 8192 + b * 2048 + g * 8;

  // ---- pass A: per-lane exp2 sums ----
  f32x4v s00 = {}, s01 = {}, s10 = {}, s11 = {};
  {
    s16x8v kA0, kA1, kA2, kA3, kB0, kB1, kB2, kB3;
    LOADK(kA, 0);
    for(int ht = 0; ht < 62; ht += 2){
      LOADK(kB, ht + 1);
      STEPA(kA);
      LOADK(kA, ht + 2);
      STEPA(kB);
    }
    LOADK(kB, 63);
    STEPA(kA);
    STEPA(kB);
  }
  float l0 = (s00[0]+s00[1]+s00[2]+s00[3]) + (s01[0]+s01[1]+s01[2]+s01[3]);
  float l1 = (s10[0]+s10[1]+s10[2]+s10[3]) + (s11[0]+s11[1]+s11[2]+s11[3]);
  l0 += __shfl_xor(l0, 16, 64); l0 += __shfl_xor(l0, 32, 64);
  l1 += __shfl_xor(l1, 16, 64); l1 += __shfl_xor(l1, 32, 64);
  const float rl0 = 1.0f / l0;
  const float rl1 = 1.0f / l1;

  // ---- pass B ----
  float* attb = ATT + (base_hb + qbase) * 2048;
  f32x4v acc00 = {}, acc01 = {}, acc02 = {}, acc03 = {};
  f32x4v acc10 = {}, acc11 = {}, acc12 = {}, acc13 = {};
  {
    s16x8v kA0, kA1, kA2, kA3, kB0, kB1, kB2, kB3;
    s16x8v vA0, vA1, vA2, vA3, vB0, vB1, vB2, vB3;
    LOADK(kA, 0); LOADV(vA, 0);
    for(int ht = 0; ht < 62; ht += 2){
      LOADK(kB, ht + 1); LOADV(vB, ht + 1);
      STEPB(kA, vA, ht);
      LOADK(kA, ht + 2); LOADV(vA, ht + 2);
      STEPB(kB, vB, ht + 1);
    }
    LOADK(kB, 63); LOADV(vB, 63);
    STEPB(kA, vA, 62);
    STEPB(kB, vB, 63);
  }

  #pragma unroll
  for(int r = 0; r < 4; ++r){
    int row0 = qbase + g * 4 + r;
    int row1 = qbase + 16 + g * 4 + r;
    u16* x0 = XC + (size_t)(b * 2048 + row0) * 512 + h * 64 + li;
    u16* x1 = XC + (size_t)(b * 2048 + row1) * 512 + h * 64 + li;
    x0[0]  = f2bf(acc00[r]); x0[16] = f2bf(acc01[r]); x0[32] = f2bf(acc02[r]); x0[48] = f2bf(acc03[r]);
    x1[0]  = f2bf(acc10[r]); x1[16] = f2bf(acc11[r]); x1[32] = f2bf(acc12[r]); x1[48] = f2bf(acc13[r]);
  }
}

// ---------------------------------------------------------------------------
// Out-projection + bias + residual + LayerNorm. 16-row tiles, 512 threads
// (8 waves x 64 cols), W double-buffered in registers. Grid 512.
__global__ __launch_bounds__(512) void k_out(const u16* __restrict__ Xb,
                                             const u16* __restrict__ Wtp,
                                             float* __restrict__ Yf,
                                             const float* __restrict__ bias,
                                             const float* __restrict__ resid,
                                             const float* __restrict__ a2,
                                             const float* __restrict__ b2){
  __shared__ __align__(16) u16 Xs[16 * 520];
  __shared__ float sred[8][16], sqred[8][16], muL[16], rsL[16];
  const int t = threadIdx.x;
  const int lane = t & 63, w = t >> 6;          // wave 0..7
  const int g = lane >> 4, li = lane & 15;
  const int i0 = blockIdx.x * 16;
  const int n0 = w * 64;

  #pragma unroll
  for(int it = 0; it < 2; ++it){
    int s = it * 512 + t, row = s >> 6, c8 = s & 63;
    u16x8v xv = *(const u16x8v*)(Xb + (size_t)(i0 + row) * 512 + c8 * 8);
    *(u16x8v*)(Xs + row * 520 + c8 * 8) = xv;
  }
  __syncthreads();

  const u16* wp0 = Wtp + (size_t)(n0 +  0 + li) * 512 + g * 8;
  const u16* wp1 = Wtp + (size_t)(n0 + 16 + li) * 512 + g * 8;
  const u16* wp2 = Wtp + (size_t)(n0 + 32 + li) * 512 + g * 8;
  const u16* wp3 = Wtp + (size_t)(n0 + 48 + li) * 512 + g * 8;

#define LOADW(S, c) { \
  S##0 = *(const s16x8v*)(wp0 + (c) * 32); \
  S##1 = *(const s16x8v*)(wp1 + (c) * 32); \
  S##2 = *(const s16x8v*)(wp2 + (c) * 32); \
  S##3 = *(const s16x8v*)(wp3 + (c) * 32); }
#define COMPW(S, c) { \
  int k0 = (c) * 32 + g * 8; \
  s16x8v a0 = *(const s16x8v*)(Xs + li * 520 + k0); \
  acc[0] = mfma16(a0, S##0, acc[0]); \
  acc[1] = mfma16(a0, S##1, acc[1]); \
  acc[2] = mfma16(a0, S##2, acc[2]); \
  acc[3] = mfma16(a0, S##3, acc[3]); }

  f32x4v acc[4] = {};
  s16x8v wA0, wA1, wA2, wA3, wB0, wB1, wB2, wB3;
  LOADW(wA, 0);
  #pragma unroll
  for(int c = 0; c < 16; c += 2){
    LOADW(wB, c + 1);
    COMPW(wA, c);
    if(c + 2 < 16) LOADW(wA, c + 2);
    COMPW(wB, c + 1);
  }
#undef LOADW
#undef COMPW

  float zres[4][4];
  #pragma unroll
  for(int j = 0; j < 4; ++j){
    int n = n0 + j * 16 + li;
    float bv = bias[n];
    #pragma unroll
    for(int r = 0; r < 4; ++r){
      int i = i0 + g * 4 + r;
      zres[j][r] = acc[j][r] + bv + resid[(size_t)i * 512 + n];
    }
  }
  #pragma unroll
  for(int r = 0; r < 4; ++r){
    float S = 0.f, SQ = 0.f;
    #pragma unroll
    for(int j = 0; j < 4; ++j){ float zz = zres[j][r]; S += zz; SQ += zz * zz; }
    #pragma unroll
    for(int off = 1; off < 16; off <<= 1){ S += __shfl_xor(S, off, 16); SQ += __shfl_xor(SQ, off, 16); }
    if(li == 0){ sred[w][g * 4 + r] = S; sqred[w][g * 4 + r] = SQ; }
  }
  __syncthreads();
  if(t < 16){
    float S = 0.f, SQ = 0.f;
    #pragma unroll
    for(int ww = 0; ww < 8; ++ww){ S += sred[ww][t]; SQ += sqred[ww][t]; }
    float mu = S * (1.0f / 512.0f);
    float var = (SQ - 512.0f * mu * mu) * (1.0f / 511.0f);
    muL[t] = mu;
    rsL[t] = 1.0f / (sqrtf(fmaxf(var, 0.0f)) + 1e-3f);
  }
  __syncthreads();
  #pragma unroll
  for(int r = 0; r < 4; ++r){
    int rloc = g * 4 + r;
    float mu = muL[rloc], rs = rsL[rloc];
    size_t ib = (size_t)(i0 + rloc) * 512;
    #pragma unroll
    for(int j = 0; j < 4; ++j){
      int n = n0 + j * 16 + li;
      Yf[ib + n] = (zres[j][r] - mu) * rs * a2[n] + b2[n];
    }
  }
}

// ---------------------------------------------------------------------------
extern "C" void kernel_launch(void* const* d_in, const int* in_sizes, int n_in,
                              void* d_out, int out_size, void* d_ws, size_t ws_size,
                              hipStream_t stream){
  const float* q      = (const float*)d_in[0];
  const float* k      = (const float*)d_in[1];
  const float* v      = (const float*)d_in[2];
  const float* w_qs   = (const float*)d_in[3];
  const float* w_ks   = (const float*)d_in[4];
  const float* w_vs   = (const float*)d_in[5];
  const float* proj_w = (const float*)d_in[6];
  const float* proj_b = (const float*)d_in[7];
  const float* a2     = (const float*)d_in[8];
  const float* b2     = (const float*)d_in[9];

  char* ws = (char*)d_ws;
  u16* wt    = (u16*)(ws);                       // 3 x 512KB (q-weights pre-scaled)
  u16* wtp   = (u16*)(ws + 1572864);             // 512KB proj_w bf16
  u16* qhh   = (u16*)(ws + 2097152);             // 8 MB head-major
  u16* khh   = (u16*)(ws + 10485760);            // 8 MB head-major
  u16* vtt   = (u16*)(ws + 18874368);            // 8 MB [n][perm(i)]
  u16* xc    = (u16*)(ws + 27262976);            // 8 MB [i][512]

  float* out = (float*)d_out;                    // (4,2048,512) fp32
  float* att = out + 4194304;                    // (32,2048,2048) fp32

  // fold 1/sqrt(512) * log2(e) into the Q projection weights
  const float qscale = 0.06375872032774575f;

  k_wall<<<dim3(4096), 256, 0, stream>>>(w_qs, w_ks, w_vs, proj_w, wt, wtp, qscale);
  k_qkv <<<dim3(256, 6), 256, 0, stream>>>(q, k, v, wt, qhh, khh, vtt);
  k_attn<<<dim3(512), 256, 0, stream>>>(qhh, khh, vtt, xc, att);
  k_out <<<dim3(512), 512, 0, stream>>>(xc, wtp, out, proj_b, q, a2, b2);
}

// Round 7
// 314.062 us; speedup vs baseline: 1.7194x; 1.0148x over previous
//
#include <hip/hip_runtime.h>
#include <stdint.h>

typedef unsigned short u16;
typedef u16   u16x4v __attribute__((ext_vector_type(4)));
typedef u16   u16x8v __attribute__((ext_vector_type(8)));
typedef short s16x8v __attribute__((ext_vector_type(8)));
typedef float f32x4v __attribute__((ext_vector_type(4)));

#define DEV static __device__ __forceinline__

// fp32 -> bf16 round-to-nearest-even (scalar)
DEV u16 f2bf(float f){
  union { float f; unsigned u; } v; v.f = f;
  unsigned r = v.u + 0x7FFFu + ((v.u >> 16) & 1u);
  return (u16)(r >> 16);
}

DEV f32x4v mfma16(s16x8v a, s16x8v b, f32x4v c){
  return __builtin_amdgcn_mfma_f32_16x16x32_bf16(a, b, c, 0, 0, 0);
}

// ---------------------------------------------------------------------------
// k_wall: all weight prep in one launch.
__global__ __launch_bounds__(256) void k_wall(const float* __restrict__ w_qs,
                                              const float* __restrict__ w_ks,
                                              const float* __restrict__ w_vs,
                                              const float* __restrict__ proj_w,
                                              u16* __restrict__ wt, u16* __restrict__ wtp,
                                              float qscale){
  int gid = blockIdx.x;
  int tsel = gid >> 10;
  int e = (gid & 1023) * 256 + threadIdx.x;
  if(tsel == 3){
    wtp[e] = f2bf(proj_w[e]);
  } else {
    const float* w = tsel == 0 ? w_qs : (tsel == 1 ? w_ks : w_vs);
    float sc = tsel == 0 ? qscale : 1.0f;
    int n = e >> 9, d = e & 511;
    int h = n >> 6, kk = n & 63;
    wt[tsel * 262144 + n * 512 + d] = f2bf(w[h * 32768 + d * 64 + kk] * sc);
  }
}

// ---------------------------------------------------------------------------
// Fused QKV projection (unchanged from r6 — passed).
__global__ __launch_bounds__(256) void k_qkv(const float* __restrict__ Q,
                                             const float* __restrict__ K,
                                             const float* __restrict__ V,
                                             const u16* __restrict__ Wt,
                                             u16* __restrict__ qhh, u16* __restrict__ khh,
                                             u16* __restrict__ vtt){
  __shared__ __align__(16) u16 Xs[32 * 520];
  const int t = threadIdx.x;
  const int lane = t & 63, w = t >> 6;
  const int g = lane >> 4, li = lane & 15;
  const int i0 = blockIdx.x * 32;
  const int y = blockIdx.y;
  const int tsel = y >> 1;
  const float* X = tsel == 0 ? Q : (tsel == 1 ? K : V);
  const int n0 = (y & 1) * 256 + w * 64;

  #pragma unroll
  for(int it = 0; it < 16; ++it){
    int s = it * 256 + t, row = s >> 7, c4 = s & 127;
    f32x4v xv = *(const f32x4v*)(X + (size_t)(i0 + row) * 512 + c4 * 4);
    u16x4v bv; bv[0]=f2bf(xv[0]); bv[1]=f2bf(xv[1]); bv[2]=f2bf(xv[2]); bv[3]=f2bf(xv[3]);
    *(u16x4v*)(Xs + row * 520 + c4 * 4) = bv;
  }
  __syncthreads();

  const int wbase = tsel * 512 + n0;
  const u16* wp0 = Wt + (size_t)(wbase +  0 + li) * 512 + g * 8;
  const u16* wp1 = Wt + (size_t)(wbase + 16 + li) * 512 + g * 8;
  const u16* wp2 = Wt + (size_t)(wbase + 32 + li) * 512 + g * 8;
  const u16* wp3 = Wt + (size_t)(wbase + 48 + li) * 512 + g * 8;

#define LOADW(S, c) { \
  S##0 = *(const s16x8v*)(wp0 + (c) * 32); \
  S##1 = *(const s16x8v*)(wp1 + (c) * 32); \
  S##2 = *(const s16x8v*)(wp2 + (c) * 32); \
  S##3 = *(const s16x8v*)(wp3 + (c) * 32); }
#define COMPW(S, c) { \
  int k0 = (c) * 32 + g * 8; \
  s16x8v a0 = *(const s16x8v*)(Xs + li * 520 + k0); \
  s16x8v a1 = *(const s16x8v*)(Xs + (16 + li) * 520 + k0); \
  acc[0][0] = mfma16(a0, S##0, acc[0][0]); acc[1][0] = mfma16(a1, S##0, acc[1][0]); \
  acc[0][1] = mfma16(a0, S##1, acc[0][1]); acc[1][1] = mfma16(a1, S##1, acc[1][1]); \
  acc[0][2] = mfma16(a0, S##2, acc[0][2]); acc[1][2] = mfma16(a1, S##2, acc[1][2]); \
  acc[0][3] = mfma16(a0, S##3, acc[0][3]); acc[1][3] = mfma16(a1, S##3, acc[1][3]); }

  f32x4v acc[2][4] = {};
  s16x8v wA0, wA1, wA2, wA3, wB0, wB1, wB2, wB3;
  LOADW(wA, 0);
  #pragma unroll
  for(int c = 0; c < 16; c += 2){
    LOADW(wB, c + 1);
    COMPW(wA, c);
    if(c + 2 < 16) LOADW(wA, c + 2);
    COMPW(wB, c + 1);
  }
#undef LOADW
#undef COMPW

  if(tsel < 2){
    u16* Y = tsel == 0 ? qhh : khh;
    #pragma unroll
    for(int rg = 0; rg < 2; ++rg)
      #pragma unroll
      for(int j = 0; j < 4; ++j){
        int n = n0 + j * 16 + li, h = n >> 6, dk = n & 63;
        #pragma unroll
        for(int r = 0; r < 4; ++r){
          int i = i0 + rg * 16 + g * 4 + r, bb = i >> 11, m = i & 2047;
          Y[((size_t)(h * 4 + bb) * 2048 + m) * 64 + dk] = f2bf(acc[rg][j][r]);
        }
      }
  } else {
    #pragma unroll
    for(int rg = 0; rg < 2; ++rg)
      #pragma unroll
      for(int j = 0; j < 4; ++j){
        int n = n0 + j * 16 + li;
        u16x4v pk;
        #pragma unroll
        for(int r = 0; r < 4; ++r) pk[r] = f2bf(acc[rg][j][r]);
        *(u16x4v*)(vtt + (size_t)n * 8192 + i0 + g * 8 + rg * 4) = pk;
      }
  }
}

// ---------------------------------------------------------------------------
// Attention, m-split: block = 4 waves = 2 q-subtiles (32 rows) x 2 m-halves
// (1024 keys). 1024 blocks -> 4 waves/SIMD. K 2-deep, V 1-deep prefetch.
// Pass A partial exp2-sums combined via LDS; PV partials combined via LDS.

#define LOADK(B, ht) { \
  const u16* _p = kp + (size_t)(ht) * 2048; \
  B##0 = *(const s16x8v*)(_p); \
  B##1 = *(const s16x8v*)(_p + 32); \
  B##2 = *(const s16x8v*)(_p + 1024); \
  B##3 = *(const s16x8v*)(_p + 1056); }

#define STEPA(B) { \
  f32x4v z0 = {}, z1 = {}; \
  z0 = mfma16(B##0, bq00, z0); z0 = mfma16(B##1, bq01, z0); \
  z1 = mfma16(B##2, bq00, z1); z1 = mfma16(B##3, bq01, z1); \
  _Pragma("unroll") for(int r = 0; r < 4; ++r){ s00[r] += exp2f(z0[r]); s01[r] += exp2f(z1[r]); } \
  f32x4v y0 = {}, y1 = {}; \
  y0 = mfma16(B##0, bq10, y0); y0 = mfma16(B##1, bq11, y0); \
  y1 = mfma16(B##2, bq10, y1); y1 = mfma16(B##3, bq11, y1); \
  _Pragma("unroll") for(int r = 0; r < 4; ++r){ s10[r] += exp2f(y0[r]); s11[r] += exp2f(y1[r]); } }

#define LOADV(ht) { \
  const u16* _p = vp + (ht) * 32; \
  vA0 = *(const s16x8v*)(_p); \
  vA1 = *(const s16x8v*)(_p + 131072); \
  vA2 = *(const s16x8v*)(_p + 262144); \
  vA3 = *(const s16x8v*)(_p + 393216); }

#define QS_HALF(KB, bqa, bqb, rl, qs_, ht) { \
  f32x4v z0 = {}, z1 = {}; \
  z0 = mfma16(KB##0, bqa, z0); z0 = mfma16(KB##1, bqb, z0); \
  z1 = mfma16(KB##2, bqa, z1); z1 = mfma16(KB##3, bqb, z1); \
  f32x4v p0, p1; \
  _Pragma("unroll") for(int r = 0; r < 4; ++r){ p0[r] = exp2f(z0[r]) * rl; p1[r] = exp2f(z1[r]) * rl; } \
  float* _ab = attb + (size_t)((qs_) * 16 + li) * 2048 + (ht) * 32 + g * 4; \
  __builtin_nontemporal_store(p0, (f32x4v*)(_ab)); \
  __builtin_nontemporal_store(p1, (f32x4v*)(_ab + 16)); \
  union { u16 hh[8]; s16x8v v; } _u; \
  _Pragma("unroll") for(int r = 0; r < 4; ++r){ _u.hh[r] = f2bf(p0[r]); _u.hh[4 + r] = f2bf(p1[r]); } \
  acc##qs_##0 = mfma16(_u.v, vA0, acc##qs_##0); \
  acc##qs_##1 = mfma16(_u.v, vA1, acc##qs_##1); \
  acc##qs_##2 = mfma16(_u.v, vA2, acc##qs_##2); \
  acc##qs_##3 = mfma16(_u.v, vA3, acc##qs_##3); }

#define STEPB(KB, ht) { \
  QS_HALF(KB, bq00, bq01, rl0, 0, ht); \
  QS_HALF(KB, bq10, bq11, rl1, 1, ht); }

__global__ __launch_bounds__(256, 4) void k_attn(const u16* __restrict__ QHH, const u16* __restrict__ KHH,
                                                 const u16* __restrict__ VTT,
                                                 u16* __restrict__ XC, float* __restrict__ ATT){
  __shared__ float Lp[2][2][32];        // [qs][mh][row]
  __shared__ float AccS[2][32][64];     // [qs][elem][lane]  = 16 KB
  const int t = threadIdx.x, lane = t & 63, w = t >> 6;
  const int g = lane >> 4, li = lane & 15;
  const int qs = w >> 1, mh = w & 1;
  // XCD swizzle: 32 q-tiles of one hb on one XCD; 4 hb per XCD
  const int gid = blockIdx.x;                // 0..1023
  const int xcd = gid & 7, rem = gid >> 3;   // rem 0..127
  const int qt = rem & 31;
  const int hb = xcd * 4 + (rem >> 5);
  const int h = hb >> 2, b = hb & 3;
  const size_t base_hb = (size_t)hb * 2048;
  const int qbase = qt * 64 + qs * 32;

  s16x8v bq00, bq01, bq10, bq11;
  {
    const u16* qp0 = QHH + (base_hb + qbase + li) * 64 + g * 8;
    const u16* qp1 = QHH + (base_hb + qbase + 16 + li) * 64 + g * 8;
    bq00 = *(const s16x8v*)(qp0); bq01 = *(const s16x8v*)(qp0 + 32);
    bq10 = *(const s16x8v*)(qp1); bq11 = *(const s16x8v*)(qp1 + 32);
  }
  // wave-local K/V/ATT bases include the m-half offset (32 ht-steps each)
  const u16* kp = KHH + (base_hb + li) * 64 + g * 8 + (size_t)mh * 65536;
  const u16* vp = VTT + (size_t)(h * 64 + li) * 8192 + b * 2048 + g * 8 + mh * 1024;
  float* attb = ATT + (base_hb + qbase) * 2048 + mh * 1024;

  // ---- pass A: per-lane exp2 partial sums over this wave's 1024 keys ----
  f32x4v s00 = {}, s01 = {}, s10 = {}, s11 = {};
  {
    s16x8v kA0, kA1, kA2, kA3, kB0, kB1, kB2, kB3;
    LOADK(kA, 0);
    for(int ht = 0; ht < 30; ht += 2){
      LOADK(kB, ht + 1);
      STEPA(kA);
      LOADK(kA, ht + 2);
      STEPA(kB);
    }
    LOADK(kB, 31);
    STEPA(kA);
    STEPA(kB);
  }
  float l0 = (s00[0]+s00[1]+s00[2]+s00[3]) + (s01[0]+s01[1]+s01[2]+s01[3]);
  float l1 = (s10[0]+s10[1]+s10[2]+s10[3]) + (s11[0]+s11[1]+s11[2]+s11[3]);
  l0 += __shfl_xor(l0, 16, 64); l0 += __shfl_xor(l0, 32, 64);
  l1 += __shfl_xor(l1, 16, 64); l1 += __shfl_xor(l1, 32, 64);
  if(lane < 16){ Lp[qs][mh][li] = l0; Lp[qs][mh][16 + li] = l1; }
  __syncthreads();
  const float rl0 = 1.0f / (Lp[qs][0][li]      + Lp[qs][1][li]);
  const float rl1 = 1.0f / (Lp[qs][0][16 + li] + Lp[qs][1][16 + li]);

  // ---- pass B over this wave's 1024 keys ----
  f32x4v acc00 = {}, acc01 = {}, acc02 = {}, acc03 = {};
  f32x4v acc10 = {}, acc11 = {}, acc12 = {}, acc13 = {};
  {
    s16x8v kA0, kA1, kA2, kA3, kB0, kB1, kB2, kB3;
    s16x8v vA0, vA1, vA2, vA3;
    LOADK(kA, 0);
    for(int ht = 0; ht < 30; ht += 2){
      LOADK(kB, ht + 1); LOADV(ht);
      STEPB(kA, ht);
      LOADK(kA, ht + 2); LOADV(ht + 1);
      STEPB(kB, ht + 1);
    }
    LOADK(kB, 31); LOADV(30);
    STEPB(kA, 30);
    LOADV(31);
    STEPB(kB, 31);
  }

  // ---- combine PV partials across m-halves ----
  if(mh == 1){
    #pragma unroll
    for(int r = 0; r < 4; ++r){
      AccS[qs][ 0 + r][lane] = acc00[r];
      AccS[qs][ 4 + r][lane] = acc01[r];
      AccS[qs][ 8 + r][lane] = acc02[r];
      AccS[qs][12 + r][lane] = acc03[r];
      AccS[qs][16 + r][lane] = acc10[r];
      AccS[qs][20 + r][lane] = acc11[r];
      AccS[qs][24 + r][lane] = acc12[r];
      AccS[qs][28 + r][lane] = acc13[r];
    }
  }
  __syncthreads();
  if(mh == 0){
    #pragma unroll
    for(int r = 0; r < 4; ++r){
      acc00[r] += AccS[qs][ 0 + r][lane];
      acc01[r] += AccS[qs][ 4 + r][lane];
      acc02[r] += AccS[qs][ 8 + r][lane];
      acc03[r] += AccS[qs][12 + r][lane];
      acc10[r] += AccS[qs][16 + r][lane];
      acc11[r] += AccS[qs][20 + r][lane];
      acc12[r] += AccS[qs][24 + r][lane];
      acc13[r] += AccS[qs][28 + r][lane];
    }
    #pragma unroll
    for(int r = 0; r < 4; ++r){
      int row0 = qbase + g * 4 + r;
      int row1 = qbase + 16 + g * 4 + r;
      u16* x0 = XC + (size_t)(b * 2048 + row0) * 512 + h * 64 + li;
      u16* x1 = XC + (size_t)(b * 2048 + row1) * 512 + h * 64 + li;
      x0[0]  = f2bf(acc00[r]); x0[16] = f2bf(acc01[r]); x0[32] = f2bf(acc02[r]); x0[48] = f2bf(acc03[r]);
      x1[0]  = f2bf(acc10[r]); x1[16] = f2bf(acc11[r]); x1[32] = f2bf(acc12[r]); x1[48] = f2bf(acc13[r]);
    }
  }
}

// ---------------------------------------------------------------------------
// Out-projection + bias + residual + LayerNorm (unchanged from r6 — passed).
__global__ __launch_bounds__(512) void k_out(const u16* __restrict__ Xb,
                                             const u16* __restrict__ Wtp,
                                             float* __restrict__ Yf,
                                             const float* __restrict__ bias,
                                             const float* __restrict__ resid,
                                             const float* __restrict__ a2,
                                             const float* __restrict__ b2){
  __shared__ __align__(16) u16 Xs[16 * 520];
  __shared__ float sred[8][16], sqred[8][16], muL[16], rsL[16];
  const int t = threadIdx.x;
  const int lane = t & 63, w = t >> 6;
  const int g = lane >> 4, li = lane & 15;
  const int i0 = blockIdx.x * 16;
  const int n0 = w * 64;

  #pragma unroll
  for(int it = 0; it < 2; ++it){
    int s = it * 512 + t, row = s >> 6, c8 = s & 63;
    u16x8v xv = *(const u16x8v*)(Xb + (size_t)(i0 + row) * 512 + c8 * 8);
    *(u16x8v*)(Xs + row * 520 + c8 * 8) = xv;
  }
  __syncthreads();

  const u16* wp0 = Wtp + (size_t)(n0 +  0 + li) * 512 + g * 8;
  const u16* wp1 = Wtp + (size_t)(n0 + 16 + li) * 512 + g * 8;
  const u16* wp2 = Wtp + (size_t)(n0 + 32 + li) * 512 + g * 8;
  const u16* wp3 = Wtp + (size_t)(n0 + 48 + li) * 512 + g * 8;

#define LOADW(S, c) { \
  S##0 = *(const s16x8v*)(wp0 + (c) * 32); \
  S##1 = *(const s16x8v*)(wp1 + (c) * 32); \
  S##2 = *(const s16x8v*)(wp2 + (c) * 32); \
  S##3 = *(const s16x8v*)(wp3 + (c) * 32); }
#define COMPW(S, c) { \
  int k0 = (c) * 32 + g * 8; \
  s16x8v a0 = *(const s16x8v*)(Xs + li * 520 + k0); \
  acc[0] = mfma16(a0, S##0, acc[0]); \
  acc[1] = mfma16(a0, S##1, acc[1]); \
  acc[2] = mfma16(a0, S##2, acc[2]); \
  acc[3] = mfma16(a0, S##3, acc[3]); }

  f32x4v acc[4] = {};
  s16x8v wA0, wA1, wA2, wA3, wB0, wB1, wB2, wB3;
  LOADW(wA, 0);
  #pragma unroll
  for(int c = 0; c < 16; c += 2){
    LOADW(wB, c + 1);
    COMPW(wA, c);
    if(c + 2 < 16) LOADW(wA, c + 2);
    COMPW(wB, c + 1);
  }
#undef LOADW
#undef COMPW

  float zres[4][4];
  #pragma unroll
  for(int j = 0; j < 4; ++j){
    int n = n0 + j * 16 + li;
    float bv = bias[n];
    #pragma unroll
    for(int r = 0; r < 4; ++r){
      int i = i0 + g * 4 + r;
      zres[j][r] = acc[j][r] + bv + resid[(size_t)i * 512 + n];
    }
  }
  #pragma unroll
  for(int r = 0; r < 4; ++r){
    float S = 0.f, SQ = 0.f;
    #pragma unroll
    for(int j = 0; j < 4; ++j){ float zz = zres[j][r]; S += zz; SQ += zz * zz; }
    #pragma unroll
    for(int off = 1; off < 16; off <<= 1){ S += __shfl_xor(S, off, 16); SQ += __shfl_xor(SQ, off, 16); }
    if(li == 0){ sred[w][g * 4 + r] = S; sqred[w][g * 4 + r] = SQ; }
  }
  __syncthreads();
  if(t < 16){
    float S = 0.f, SQ = 0.f;
    #pragma unroll
    for(int ww = 0; ww < 8; ++ww){ S += sred[ww][t]; SQ += sqred[ww][t]; }
    float mu = S * (1.0f / 512.0f);
    float var = (SQ - 512.0f * mu * mu) * (1.0f / 511.0f);
    muL[t] = mu;
    rsL[t] = 1.0f / (sqrtf(fmaxf(var, 0.0f)) + 1e-3f);
  }
  __syncthreads();
  #pragma unroll
  for(int r = 0; r < 4; ++r){
    int rloc = g * 4 + r;
    float mu = muL[rloc], rs = rsL[rloc];
    size_t ib = (size_t)(i0 + rloc) * 512;
    #pragma unroll
    for(int j = 0; j < 4; ++j){
      int n = n0 + j * 16 + li;
      Yf[ib + n] = (zres[j][r] - mu) * rs * a2[n] + b2[n];
    }
  }
}

// ---------------------------------------------------------------------------
extern "C" void kernel_launch(void* const* d_in, const int* in_sizes, int n_in,
                              void* d_out, int out_size, void* d_ws, size_t ws_size,
                              hipStream_t stream){
  const float* q      = (const float*)d_in[0];
  const float* k      = (const float*)d_in[1];
  const float* v      = (const float*)d_in[2];
  const float* w_qs   = (const float*)d_in[3];
  const float* w_ks   = (const float*)d_in[4];
  const float* w_vs   = (const float*)d_in[5];
  const float* proj_w = (const float*)d_in[6];
  const float* proj_b = (const float*)d_in[7];
  const float* a2     = (const float*)d_in[8];
  const float* b2     = (const float*)d_in[9];

  char* ws = (char*)d_ws;
  u16* wt    = (u16*)(ws);                       // 3 x 512KB (q-weights pre-scaled)
  u16* wtp   = (u16*)(ws + 1572864);             // 512KB proj_w bf16
  u16* qhh   = (u16*)(ws + 2097152);             // 8 MB head-major
  u16* khh   = (u16*)(ws + 10485760);            // 8 MB head-major
  u16* vtt   = (u16*)(ws + 18874368);            // 8 MB [n][perm(i)]
  u16* xc    = (u16*)(ws + 27262976);            // 8 MB [i][512]

  float* out = (float*)d_out;                    // (4,2048,512) fp32
  float* att = out + 4194304;                    // (32,2048,2048) fp32

  // fold 1/sqrt(512) * log2(e) into the Q projection weights
  const float qscale = 0.06375872032774575f;

  k_wall<<<dim3(4096), 256, 0, stream>>>(w_qs, w_ks, w_vs, proj_w, wt, wtp, qscale);
  k_qkv <<<dim3(256, 6), 256, 0, stream>>>(q, k, v, wt, qhh, khh, vtt);
  k_attn<<<dim3(1024), 256, 0, stream>>>(qhh, khh, vtt, xc, att);
  k_out <<<dim3(512), 512, 0, stream>>>(xc, wtp, out, proj_b, q, a2, b2);
}